// Round 1
// 343.503 us; speedup vs baseline: 1.1088x; 1.1088x over previous
//
#include <hip/hip_runtime.h>
#include <cstdint>
#include <cstddef>

#define BATCH 256
#define VOCAB 128000
#define V4 (VOCAB/4)
#define NBINS 4096
#define CAP 4096            // power of 2: bitonic padding can never overflow

__device__ __forceinline__ uint32_t rotl32(uint32_t v, int r){ return (v<<r)|(v>>(32-r)); }

// threefry2x32 with key (0,1) — jax.random.key(1) -> key data [0,1]
__device__ __forceinline__ void threefry2x32_01(uint32_t& x0, uint32_t& x1){
  const uint32_t ks0=0u, ks1=1u, ks2=0x1BD11BDAu ^ 0u ^ 1u;
  x0+=ks0; x1+=ks1;
#define TF_R(r) { x0+=x1; x1=rotl32(x1,(r)); x1^=x0; }
  TF_R(13) TF_R(15) TF_R(26) TF_R(6)
  x0+=ks1; x1+=ks2+1u;
  TF_R(17) TF_R(29) TF_R(16) TF_R(24)
  x0+=ks2; x1+=ks0+2u;
  TF_R(13) TF_R(15) TF_R(26) TF_R(6)
  x0+=ks0; x1+=ks1+3u;
  TF_R(17) TF_R(29) TF_R(16) TF_R(24)
  x0+=ks1; x1+=ks2+4u;
  TF_R(13) TF_R(15) TF_R(26) TF_R(6)
  x0+=ks2; x1+=ks0+5u;
#undef TF_R
}

// JAX partitionable threefry 32-bit draw: counter=(0,z), bits = x0 ^ x1 (XOR-fold).
// Verified correct in prior session (absmax 0).
__device__ __forceinline__ float gumbel_at(uint32_t z){
  uint32_t x0 = 0u, x1 = z;
  threefry2x32_01(x0, x1);
  uint32_t bits = x0 ^ x1;
  uint32_t fb = (bits >> 9) | 0x3F800000u;
  float f = __uint_as_float(fb) - 1.0f;
  const float tiny = 1.17549435e-38f;
  float u = fmaxf(tiny, f + tiny);
  return -logf(-logf(u));
}

__device__ __forceinline__ uint32_t fkey(uint32_t u){
  return (u >> 31) ? ~u : (u | 0x80000000u);
}
__device__ __forceinline__ float pdecode(unsigned long long k){
  return __uint_as_float(~(uint32_t)(k >> 32));
}

// One block per row, TWO streaming passes (was three):
//   pass 1: fill out-row + row max + UNGATED count-only histogram (LDS atomics)
//   scan:   maximal top-bin set under CAP (count-based; superset of the old
//           mass-based set => identical sorted prefix & identical sample)
//   pass 2: D sum + candidate extraction fused
// then: re-encode p, bitonic sort, cumsum cutoff, gumbel argmax, 1e5 write.
__global__ __launch_bounds__(1024) void k_main(
    const float* __restrict__ scores, const float* __restrict__ green,
    float* __restrict__ out)
{
  __shared__ union {
    unsigned cnt[NBINS];                         // 16 KB (pass 1 + scan)
    unsigned long long skeys[CAP];               // 32 KB (pass 2 onward)
  } u;
  __shared__ float red[1024];
  __shared__ unsigned long long wavewin[16];
  __shared__ unsigned n_sh, thr_sh;
  __shared__ int cut_sh;

  const int b = blockIdx.x, tid = threadIdx.x;
  const float4* row4 = (const float4*)(scores + (size_t)b * VOCAB);
  const float4* grn4 = (const float4*)green;
  float* orow = out + (size_t)b * VOCAB;

  // 0) zero histogram
  for (int i = tid; i < NBINS; i += 1024) u.cnt[i] = 0u;
  __syncthreads();

  // 1) single read pass: fill output row, exact row max, ungated count hist.
  //    fmax accumulation order identical to verified kernel (x,y,z,w per i).
  {
    const float4 fv = make_float4(1e-5f, 1e-5f, 1e-5f, 1e-5f);
    float4* o4 = (float4*)orow;
    float lm = -INFINITY;
    for (int i = tid; i < V4; i += 1024){
      float4 s = row4[i], g = grn4[i];
      o4[i] = fv;
      #pragma unroll
      for (int c = 0; c < 4; ++c){
        float l = fmaf(2.f, (&g.x)[c], (&s.x)[c]);
        lm = fmaxf(lm, l);
        atomicAdd(&u.cnt[fkey(__float_as_uint(l)) >> 20], 1u);
      }
    }
    red[tid] = lm;
  }
  __syncthreads();
  for (int s = 512; s > 0; s >>= 1){ if (tid < s) red[tid] = fmaxf(red[tid], red[tid+s]); __syncthreads(); }
  const float m = red[0];
  __syncthreads();                       // all threads read m before red reuse

  // 2) threshold: maximal set of top bins with total count <= CAP (thread 0).
  //    Superset of the previous mass-based scan's set => the sorted prefix up
  //    to the 0.9 crossing (and thus cut/gumbel/sample) is unchanged.
  if (tid == 0){
    int top = (int)(fkey(__float_as_uint(m)) >> 20);   // bins above bin(m) empty
    unsigned c = 0; unsigned result = (unsigned)top;
    for (int bin = top; bin >= 0; --bin){
      unsigned cb = u.cnt[bin];
      if (c + cb > CAP) break;
      c += cb; result = (unsigned)bin;
    }
    thr_sh = result; n_sh = 0u;
  }
  __syncthreads();                      // hist reads done; skeys (union) writable
  const unsigned thr = thr_sh;

  // 3) second read pass: D sum (all elements, same accumulation order as
  //    verified kernel) fused with candidate extraction into LDS.
  float ls = 0.f;
  for (int i = tid; i < V4; i += 1024){
    float4 s = row4[i], g = grn4[i];
    #pragma unroll
    for (int c = 0; c < 4; ++c){
      float l = fmaf(2.f, (&g.x)[c], (&s.x)[c]);
      ls += expf(l - m);
      uint32_t lb = __float_as_uint(l);
      if ((fkey(lb) >> 20) >= thr){
        unsigned pos = atomicAdd(&n_sh, 1u);
        if (pos < CAP) u.skeys[pos] = ((unsigned long long)lb << 32) | (unsigned)(4*i + c);
      }
    }
  }
  red[tid] = ls; __syncthreads();
  for (int s = 512; s > 0; s >>= 1){ if (tid < s) red[tid] += red[tid+s]; __syncthreads(); }
  const float D = red[0];
  unsigned n = n_sh; if (n > CAP) n = CAP;   // scan guarantees <= CAP

  // 4) re-encode candidates with p = exp(l-m)/D; key = (~p_bits, idx) => p desc, idx asc
  for (unsigned j = tid; j < n; j += 1024){
    unsigned long long k = u.skeys[j];
    float l = __uint_as_float((uint32_t)(k >> 32));
    float p = expf(l - m) / D;
    u.skeys[j] = ((unsigned long long)(~__float_as_uint(p)) << 32) | (k & 0xFFFFFFFFull);
  }
  unsigned N2 = 2; while (N2 < n) N2 <<= 1;
  for (unsigned i = n + tid; i < N2; i += 1024) u.skeys[i] = 0xFFFFFFFFFFFFFFFFull;
  __syncthreads();

  // 5) bitonic sort (ascending == p desc, stable via embedded idx)
  for (unsigned k = 2; k <= N2; k <<= 1){
    for (unsigned j = k >> 1; j > 0; j >>= 1){
      for (unsigned i = tid; i < N2; i += 1024){
        unsigned ixj = i ^ j;
        if (ixj > i){
          unsigned long long a = u.skeys[i], c2 = u.skeys[ixj];
          bool up = ((i & k) == 0u);
          if ((a > c2) == up){ u.skeys[i] = c2; u.skeys[ixj] = a; }
        }
      }
      __syncthreads();
    }
  }

  // 6) 0.9 cumsum crossing (chunked partials in red[], thread-0 walk)
  unsigned C = (n + 1023) >> 10;
  {
    unsigned lo = tid * C; if (lo > n) lo = n;
    unsigned hi = lo + C;  if (hi > n) hi = n;
    float s = 0.f;
    for (unsigned j = lo; j < hi; ++j) s += pdecode(u.skeys[j]);
    red[tid] = s;
  }
  __syncthreads();
  if (tid == 0){
    float run = 0.f; int cut = (int)n - 1; int t = 0;
    for (; t < 1024; ++t){ float cs = red[t]; if (run + cs >= 0.9f) break; run += cs; }
    if (t < 1024){
      float c2 = run;
      for (unsigned j = (unsigned)t * C; j < n; ++j){
        c2 += pdecode(u.skeys[j]);
        if (c2 >= 0.9f){ cut = (int)j; break; }
      }
    }
    cut_sh = cut;
  }
  __syncthreads();
  const int cut = cut_sh;

  // 7) gumbel argmax over sorted positions 0..cut
  float best = -INFINITY; unsigned bj = 0x7FFFFFFFu;
  for (int j = tid; j <= cut; j += 1024){
    float p = pdecode(u.skeys[j]);
    float sc = logf(p) + gumbel_at((uint32_t)b * (uint32_t)VOCAB + (uint32_t)j);
    if (sc > best || (sc == best && (unsigned)j < bj)){ best = sc; bj = (unsigned)j; }
  }
  for (int off = 32; off > 0; off >>= 1){
    float osc = __shfl_down(best, off, 64);
    unsigned oj = __shfl_down(bj, off, 64);
    if (osc > best || (osc == best && oj < bj)){ best = osc; bj = oj; }
  }
  if ((tid & 63) == 0){
    uint32_t ub = __float_as_uint(best);
    uint32_t ou = (ub >> 31) ? ~ub : (ub | 0x80000000u);
    wavewin[tid >> 6] = ((unsigned long long)ou << 32) |
                        (unsigned long long)(0xFFFFFFFFu - bj);   // tie -> min j
  }
  __syncthreads();
  if (tid == 0){
    unsigned long long bb = 0ull;
    for (int w = 0; w < 16; ++w){ unsigned long long x = wavewin[w]; if (x > bb) bb = x; }
    unsigned jwin = 0xFFFFFFFFu - (unsigned)(bb & 0xFFFFFFFFull);
    // fill-write of 1e-5 at this address is ordered before us by the barriers'
    // vmcnt(0) drain (same block); write winner directly — k_set eliminated.
    orow[(size_t)(u.skeys[jwin] & 0xFFFFFFFFull)] = 1e5f;
  }
}

extern "C" void kernel_launch(void* const* d_in, const int* in_sizes, int n_in,
                              void* d_out, int out_size, void* d_ws, size_t ws_size,
                              hipStream_t stream) {
  // d_in[0]=input_ids (unused), d_in[1]=scores [256*128000] f32, d_in[2]=green [128000] f32
  const float* scores = (const float*)d_in[1];
  const float* green  = (const float*)d_in[2];
  float* out = (float*)d_out;
  (void)d_ws; (void)ws_size;

  hipLaunchKernelGGL(k_main, dim3(BATCH), dim3(1024), 0, stream, scores, green, out);
}